// Round 10
// baseline (493.053 us; speedup 1.0000x reference)
//
#include <hip/hip_runtime.h>
#include <math.h>

#define NN 50000
#define EE 800000
#define IN_C 128
#define HID 64
#define HEADS 4
#define SCAN_BLOCKS ((NN + 255) / 256)   // 196
#define EBLOCKS ((EE + 255) / 256)       // 3125

typedef __attribute__((ext_vector_type(8))) short bf16x8;
typedef __attribute__((ext_vector_type(4))) float f32x4;

#if defined(__has_builtin)
#if __has_builtin(__builtin_amdgcn_fdot2_f32_bf16)
#define HAVE_FDOT2_BF16 1
#endif
#if __has_builtin(__builtin_amdgcn_cvt_pk_bf16_f32)
#define HAVE_PK_BF16 1
#endif
#endif

// ---------------- helpers ----------------

__device__ inline unsigned short f2bf(float f) {       // fp32 -> bf16 RNE
    unsigned u = __float_as_uint(f);
    return (unsigned short)((u + 0x7fff + ((u >> 16) & 1)) >> 16);
}
__device__ inline float bf2f(unsigned short s) {
    return __uint_as_float(((unsigned)s) << 16);
}
#ifdef HAVE_PK_BF16
typedef __attribute__((ext_vector_type(2))) __bf16 bf16x2_t;
__device__ inline unsigned pk2bf(float a, float b) {   // low=a, high=b, RNE
    bf16x2_t r = __builtin_amdgcn_cvt_pk_bf16_f32(a, b);
    return __builtin_bit_cast(unsigned, r);
}
#else
__device__ inline unsigned pk2bf(float a, float b) {
    return (unsigned)f2bf(a) | ((unsigned)f2bf(b) << 16);
}
#endif
__device__ inline unsigned prm(unsigned a, unsigned b, unsigned sel) {
    return __builtin_amdgcn_perm(a, b, sel);
}
#ifdef HAVE_FDOT2_BF16
typedef __attribute__((ext_vector_type(2))) __bf16 bf2v;
__device__ inline float fdot2bf(unsigned h, unsigned w, float acc) {
    return __builtin_amdgcn_fdot2_f32_bf16(__builtin_bit_cast(bf2v, h),
                                           __builtin_bit_cast(bf2v, w), acc, false);
}
#else
__device__ inline float fdot2bf(unsigned h, unsigned w, float acc) {
    return acc + bf2f((unsigned short)(h & 0xffff)) * bf2f((unsigned short)(w & 0xffff))
               + bf2f((unsigned short)(h >> 16)) * bf2f((unsigned short)(w >> 16));
}
#endif

__device__ inline int wave_incl_scan(int v, int lane) {
    #pragma unroll
    for (int off = 1; off < 64; off <<= 1) {
        int t = __shfl_up(v, off);
        if (lane >= off) v += t;
    }
    return v;
}

__device__ inline int block256_excl_scan(int v, int tid, int* ws4) {
    int lane = tid & 63, wv = tid >> 6;
    int incl = wave_incl_scan(v, lane);
    if (lane == 63) ws4[wv] = incl;
    __syncthreads();
    if (tid == 0) {
        int run = 0;
        #pragma unroll
        for (int i = 0; i < 4; i++) { int t = ws4[i]; ws4[i] = run; run += t; }
    }
    __syncthreads();
    return incl + ws4[wv] - v;
}

// ---------------- front: degree histogram (+edge ranks) + weight splits ----------------

__global__ void front_kernel(const int* __restrict__ ei, int* __restrict__ deg,
                             unsigned short* __restrict__ rank,
                             const float* __restrict__ W1, unsigned short* __restrict__ W1Thi,
                             unsigned short* __restrict__ W1Tlo,
                             const float* __restrict__ W2, unsigned short* __restrict__ W2Thi,
                             unsigned short* __restrict__ W2Tlo) {
    int b = blockIdx.x;
    int tid = threadIdx.x;
    if (b < EBLOCKS) {
        int i = b * 256 + tid;
        if (i < EE) rank[i] = (unsigned short)atomicAdd(&deg[ei[EE + i]], 1);
    } else if (b < EBLOCKS + 128) {
        int idx = (b - EBLOCKS) * 256 + tid;         // W1 [128][256]
        int r = idx >> 8, c = idx & 255;
        float v = W1[idx];
        unsigned short h = f2bf(v);
        W1Thi[c * 128 + r] = h;
        W1Tlo[c * 128 + r] = f2bf(v - bf2f(h));
    } else {
        int idx = (b - EBLOCKS - 128) * 256 + tid;   // W2 [256][64]
        int r = idx >> 6, c = idx & 63;
        float v = W2[idx];
        unsigned short h = f2bf(v);
        W2Thi[c * 256 + r] = h;
        W2Tlo[c * 256 + r] = f2bf(v - bf2f(h));
    }
}

// ---------------- single-pass CSR scan (decoupled lookback) ----------------
__global__ void scan_fill_kernel(const int* __restrict__ deg,
                                 unsigned long long* __restrict__ desc,
                                 int* __restrict__ row_ptr) {
    __shared__ int ws4[4];
    __shared__ int sbase;
    int b = blockIdx.x, tid = threadIdx.x;
    int idx = b * 256 + tid;
    int d = (idx < NN) ? deg[idx] : 0;
    int excl = block256_excl_scan(d, tid, ws4);
    if (tid == 255) {
        unsigned total = (unsigned)(excl + d);
        __threadfence();
        atomicExch(&desc[b], (1ULL << 32) | (unsigned long long)total);
    }
    if (tid < 64) {
        int sum = 0;
        int hi = b;
        while (hi > 0) {
            int lo = hi - 64; if (lo < 0) lo = 0;
            int myi = lo + tid;
            unsigned v = 0;
            if (myi < hi) {
                unsigned long long d8;
                do { d8 = atomicAdd(&desc[myi], 0ULL); } while ((d8 >> 32) == 0);
                v = (unsigned)(d8 & 0xffffffffULL);
            }
            #pragma unroll
            for (int off = 32; off; off >>= 1) v += __shfl_down(v, off);
            v = __shfl(v, 0);
            sum += (int)v;
            hi = lo;
        }
        if (tid == 0) sbase = sum;
    }
    __syncthreads();
    int gbase = sbase;
    if (idx < NN) row_ptr[idx] = gbase + excl;
    if (b == gridDim.x - 1 && tid == 255) row_ptr[NN] = gbase + excl + d;  // == EE
}

// atomic-free scatter: position = row_ptr[dst] + precomputed rank (u16 ids)
__global__ void scatter_kernel(const int* __restrict__ ei, const unsigned short* __restrict__ rank,
                               const int* __restrict__ row_ptr, unsigned short* __restrict__ csr_src) {
    int i = blockIdx.x * blockDim.x + threadIdx.x;
    if (i < EE) {
        int d = ei[EE + i];
        csr_src[row_ptr[d] + (int)rank[i]] = (unsigned short)ei[i];
    }
}

// ---------------- layer-1 MFMA GEMM + fused alpha ----------------
__global__ __launch_bounds__(256) void gemm1_mfma(
        const float* __restrict__ x,
        const unsigned short* __restrict__ Bhi, const unsigned short* __restrict__ Blo,
        const float* __restrict__ a_src, const float* __restrict__ a_dst,
        unsigned short* __restrict__ h1b, float* __restrict__ as1, float* __restrict__ ad1) {
    __shared__ unsigned short Ahi[64][136];   // +8 pad
    __shared__ unsigned short Alo[64][136];
    int tid = threadIdx.x;
    int w = tid >> 6, lane = tid & 63;
    int lq = lane >> 4, lr = lane & 15;
    int brow = blockIdx.x * 64;
    {
        int row = tid >> 2;                    // 0..63
        int col0 = (tid & 3) * 32;             // 0,32,64,96
        int gr = min(brow + row, NN - 1);
        #pragma unroll
        for (int i = 0; i < 32; i += 4) {
            float4 v = *(const float4*)(x + (size_t)gr * 128 + col0 + i);
            unsigned h01 = pk2bf(v.x, v.y);
            unsigned h23 = pk2bf(v.z, v.w);
            float rx = v.x - __uint_as_float(h01 << 16);
            float ry = v.y - __uint_as_float(h01 & 0xffff0000u);
            float rz = v.z - __uint_as_float(h23 << 16);
            float rw = v.w - __uint_as_float(h23 & 0xffff0000u);
            *(unsigned*)&Ahi[row][col0 + i]     = h01;
            *(unsigned*)&Ahi[row][col0 + i + 2] = h23;
            *(unsigned*)&Alo[row][col0 + i]     = pk2bf(rx, ry);
            *(unsigned*)&Alo[row][col0 + i + 2] = pk2bf(rz, rw);
        }
    }
    __syncthreads();
    f32x4 acc[4][4];
    f32x4 zf = {0.f, 0.f, 0.f, 0.f};
    #pragma unroll
    for (int mi = 0; mi < 4; mi++)
        #pragma unroll
        for (int ni = 0; ni < 4; ni++) acc[mi][ni] = zf;
    #pragma unroll
    for (int q = 0; q < 4; q++) {
        int ko = q * 32 + lq * 8;
        bf16x8 ah[4], al[4];
        #pragma unroll
        for (int mi = 0; mi < 4; mi++) {
            ah[mi] = *(const bf16x8*)(const void*)&Ahi[mi * 16 + lr][ko];
            al[mi] = *(const bf16x8*)(const void*)&Alo[mi * 16 + lr][ko];
        }
        #pragma unroll
        for (int ni = 0; ni < 4; ni++) {
            size_t bo = (size_t)(w * 64 + ni * 16 + lr) * 128 + ko;
            bf16x8 bh = *(const bf16x8*)(const void*)(Bhi + bo);
            bf16x8 bl = *(const bf16x8*)(const void*)(Blo + bo);
            #pragma unroll
            for (int mi = 0; mi < 4; mi++) {
                acc[mi][ni] = __builtin_amdgcn_mfma_f32_16x16x32_bf16(al[mi], bh, acc[mi][ni], 0, 0, 0);
                acc[mi][ni] = __builtin_amdgcn_mfma_f32_16x16x32_bf16(ah[mi], bl, acc[mi][ni], 0, 0, 0);
                acc[mi][ni] = __builtin_amdgcn_mfma_f32_16x16x32_bf16(ah[mi], bh, acc[mi][ni], 0, 0, 0);
            }
        }
    }
    float asv[4], adv[4];
    #pragma unroll
    for (int ni = 0; ni < 4; ni++) {
        asv[ni] = a_src[w * 64 + ni * 16 + lr];
        adv[ni] = a_dst[w * 64 + ni * 16 + lr];
    }
    #pragma unroll
    for (int mi = 0; mi < 4; mi++) {
        f32x4 ps = zf, pd = zf;
        #pragma unroll
        for (int ni = 0; ni < 4; ni++)
            #pragma unroll
            for (int r = 0; r < 4; r++) {
                ps[r] += acc[mi][ni][r] * asv[ni];
                pd[r] += acc[mi][ni][r] * adv[ni];
            }
        #pragma unroll
        for (int m = 1; m < 16; m <<= 1)
            #pragma unroll
            for (int r = 0; r < 4; r++) {
                ps[r] += __shfl_xor(ps[r], m);
                pd[r] += __shfl_xor(pd[r], m);
            }
        #pragma unroll
        for (int r = 0; r < 4; r++) {
            int n = brow + mi * 16 + lq * 4 + r;
            if (lr == 0 && n < NN) { as1[n * 4 + w] = ps[r]; ad1[n * 4 + w] = pd[r]; }
        }
        #pragma unroll
        for (int ni = 0; ni < 4; ni++)
            #pragma unroll
            for (int r = 0; r < 4; r++) {
                int n = brow + mi * 16 + lq * 4 + r;
                if (n < NN)
                    h1b[(size_t)n * 256 + w * 64 + ni * 16 + lr] = f2bf(acc[mi][ni][r]);
            }
    }
}

// ---------------- pass A: pre-normalized bf16 edge weights (head-major [4][E]) ----------------
__global__ __launch_bounds__(256) void wnorm_kernel(
        const int* __restrict__ row_ptr, const unsigned short* __restrict__ csr_src,
        const float* __restrict__ as, const float* __restrict__ ad,
        unsigned short* __restrict__ wnorm) {
    int tid = threadIdx.x;
    int wv = tid >> 6, lane = tid & 63;
    int n = blockIdx.x * 4 + wv;
    if (n >= NN) return;
    int start = row_ptr[n], end = row_ptr[n + 1];
    float4 adv = ((const float4*)ad)[n];
    float d0 = 0.f, d1 = 0.f, d2 = 0.f, d3 = 0.f;
    for (int i = start + lane; i < end; i += 64) {
        int s = (int)csr_src[i];
        float4 a = ((const float4*)as)[s];
        float e;
        e = a.x + adv.x; e = e > 0.f ? e : 0.2f * e; d0 += __expf(e);
        e = a.y + adv.y; e = e > 0.f ? e : 0.2f * e; d1 += __expf(e);
        e = a.z + adv.z; e = e > 0.f ? e : 0.2f * e; d2 += __expf(e);
        e = a.w + adv.w; e = e > 0.f ? e : 0.2f * e; d3 += __expf(e);
    }
    #pragma unroll
    for (int off = 32; off; off >>= 1) {
        d0 += __shfl_down(d0, off); d1 += __shfl_down(d1, off);
        d2 += __shfl_down(d2, off); d3 += __shfl_down(d3, off);
    }
    d0 = __shfl(d0, 0); d1 = __shfl(d1, 0);
    d2 = __shfl(d2, 0); d3 = __shfl(d3, 0);
    float i0 = 1.f / (d0 + 1e-16f), i1 = 1.f / (d1 + 1e-16f);
    float i2 = 1.f / (d2 + 1e-16f), i3 = 1.f / (d3 + 1e-16f);
    for (int i = start + lane; i < end; i += 64) {
        int s = (int)csr_src[i];
        float4 a = ((const float4*)as)[s];
        float e;
        e = a.x + adv.x; e = e > 0.f ? e : 0.2f * e;
        wnorm[(size_t)0 * EE + i] = f2bf(__expf(e) * i0);
        e = a.y + adv.y; e = e > 0.f ? e : 0.2f * e;
        wnorm[(size_t)1 * EE + i] = f2bf(__expf(e) * i1);
        e = a.z + adv.z; e = e > 0.f ? e : 0.2f * e;
        wnorm[(size_t)2 * EE + i] = f2bf(__expf(e) * i2);
        e = a.w + adv.w; e = e > 0.f ? e : 0.2f * e;
        wnorm[(size_t)3 * EE + i] = f2bf(__expf(e) * i3);
    }
}

// ---------------- pass B: XCD-sliced layer-1 aggregation ----------------
// slice = blockIdx & 7 (8 slices x 32 ch); under round-robin dispatch each XCD
// gathers only its 3.2 MB slice of h1b -> L2-resident. 4 nodes per block (wave=node).
// Output h2s slice-major: [8][NN][32].
__global__ __launch_bounds__(256) void agg1s_kernel(
        const unsigned short* __restrict__ h1b, const int* __restrict__ row_ptr,
        const unsigned short* __restrict__ csr_src, const unsigned short* __restrict__ wnorm,
        const float* __restrict__ b1, unsigned short* __restrict__ h2s) {
    __shared__ int            ssrc[4][64];
    __shared__ unsigned short swt[4][64];
    int tid = threadIdx.x;
    int wv = tid >> 6, lane = tid & 63;
    int sl = blockIdx.x & 7;
    int n = (blockIdx.x >> 3) * 4 + wv;
    if (n >= NN) return;
    const unsigned short* wH = wnorm + (size_t)(sl >> 1) * EE;
    int start = row_ptr[n], end = row_ptr[n + 1];
    int e8 = lane >> 2;      // 0..15 edges in flight
    int q  = lane & 3;       // channel-quad (8 ch)
    float acc[8] = {};
    for (int c0 = start; c0 < end; c0 += 64) {
        int m = min(64, end - c0);
        if (lane < m) {
            ssrc[wv][lane] = (int)csr_src[c0 + lane];
            swt[wv][lane]  = wH[c0 + lane];
        } else {
            ssrc[wv][lane] = 0;
            swt[wv][lane]  = 0;
        }
        for (int j = 0; j < m; j += 16) {
            int ee = j + e8;
            int src = ssrc[wv][ee];
            float w = bf2f(swt[wv][ee]);      // 0 for padded edges
            uint4 hv = *(const uint4*)(const void*)(h1b + (size_t)src * 256 + sl * 32 + q * 8);
            acc[0] += __uint_as_float(hv.x << 16) * w;
            acc[1] += __uint_as_float(hv.x & 0xffff0000u) * w;
            acc[2] += __uint_as_float(hv.y << 16) * w;
            acc[3] += __uint_as_float(hv.y & 0xffff0000u) * w;
            acc[4] += __uint_as_float(hv.z << 16) * w;
            acc[5] += __uint_as_float(hv.z & 0xffff0000u) * w;
            acc[6] += __uint_as_float(hv.w << 16) * w;
            acc[7] += __uint_as_float(hv.w & 0xffff0000u) * w;
        }
    }
    #pragma unroll
    for (int msk = 4; msk < 64; msk <<= 1)
        #pragma unroll
        for (int k = 0; k < 8; k++) acc[k] += __shfl_xor(acc[k], msk);
    if (lane < 4) {                           // lane == q group holder
        float r[8];
        #pragma unroll
        for (int k = 0; k < 8; k++) {
            float v = acc[k] + b1[sl * 32 + lane * 8 + k];
            r[k] = v > 0.f ? v : expm1f(v);
        }
        uint4 o;
        o.x = pk2bf(r[0], r[1]); o.y = pk2bf(r[2], r[3]);
        o.z = pk2bf(r[4], r[5]); o.w = pk2bf(r[6], r[7]);
        *(uint4*)(void*)(h2s + ((size_t)sl * NN + n) * 32 + lane * 8) = o;
    }
}

// ---------------- layer-2 MFMA GEMM + fused alpha (A in slice-major h2s) ----------------
__global__ __launch_bounds__(256) void gemm2_mfma(
        const unsigned short* __restrict__ h2s,
        const unsigned short* __restrict__ Bhi, const unsigned short* __restrict__ Blo,
        const float* __restrict__ a_src, const float* __restrict__ a_dst,
        unsigned short* __restrict__ g2b, float* __restrict__ as2, float* __restrict__ ad2) {
    int tid = threadIdx.x;
    int w = tid >> 6, lane = tid & 63;
    int lq = lane >> 4, lr = lane & 15;
    int wrow = blockIdx.x * 128 + w * 32;
    f32x4 acc[2][4];
    f32x4 zf = {0.f, 0.f, 0.f, 0.f};
    #pragma unroll
    for (int mi = 0; mi < 2; mi++)
        #pragma unroll
        for (int ni = 0; ni < 4; ni++) acc[mi][ni] = zf;
    int ra = min(wrow + lr, NN - 1);
    int rb = min(wrow + 16 + lr, NN - 1);
    #pragma unroll
    for (int q = 0; q < 8; q++) {             // K-chunk q == slice q of h2s
        bf16x8 ah0 = *(const bf16x8*)(const void*)(h2s + ((size_t)q * NN + ra) * 32 + lq * 8);
        bf16x8 ah1 = *(const bf16x8*)(const void*)(h2s + ((size_t)q * NN + rb) * 32 + lq * 8);
        int ko = q * 32 + lq * 8;
        #pragma unroll
        for (int ni = 0; ni < 4; ni++) {
            size_t bo = (size_t)(ni * 16 + lr) * 256 + ko;
            bf16x8 bh = *(const bf16x8*)(const void*)(Bhi + bo);
            bf16x8 bl = *(const bf16x8*)(const void*)(Blo + bo);
            acc[0][ni] = __builtin_amdgcn_mfma_f32_16x16x32_bf16(ah0, bl, acc[0][ni], 0, 0, 0);
            acc[0][ni] = __builtin_amdgcn_mfma_f32_16x16x32_bf16(ah0, bh, acc[0][ni], 0, 0, 0);
            acc[1][ni] = __builtin_amdgcn_mfma_f32_16x16x32_bf16(ah1, bl, acc[1][ni], 0, 0, 0);
            acc[1][ni] = __builtin_amdgcn_mfma_f32_16x16x32_bf16(ah1, bh, acc[1][ni], 0, 0, 0);
        }
    }
    float asv[4], adv[4];
    #pragma unroll
    for (int ni = 0; ni < 4; ni++) {
        asv[ni] = a_src[ni * 16 + lr];
        adv[ni] = a_dst[ni * 16 + lr];
    }
    #pragma unroll
    for (int mi = 0; mi < 2; mi++) {
        f32x4 ps = zf, pd = zf;
        #pragma unroll
        for (int ni = 0; ni < 4; ni++)
            #pragma unroll
            for (int r = 0; r < 4; r++) {
                ps[r] += acc[mi][ni][r] * asv[ni];
                pd[r] += acc[mi][ni][r] * adv[ni];
            }
        #pragma unroll
        for (int m = 1; m < 16; m <<= 1)
            #pragma unroll
            for (int r = 0; r < 4; r++) {
                ps[r] += __shfl_xor(ps[r], m);
                pd[r] += __shfl_xor(pd[r], m);
            }
        #pragma unroll
        for (int r = 0; r < 4; r++) {
            int n = wrow + mi * 16 + lq * 4 + r;
            if (lr == 0 && n < NN) { as2[n] = ps[r]; ad2[n] = pd[r]; }
        }
        #pragma unroll
        for (int ni = 0; ni < 4; ni++)
            #pragma unroll
            for (int r = 0; r < 4; r++) {
                int n = wrow + mi * 16 + lq * 4 + r;
                if (n < NN)
                    g2b[(size_t)n * 64 + ni * 16 + lr] = f2bf(acc[mi][ni][r]);
            }
    }
}

// ---------------- layer-2 aggregation: edge-paired dot2 gather, unroll-8 ----------------
__global__ __launch_bounds__(256) void agg2_kernel(
        const unsigned short* __restrict__ g2b, const int* __restrict__ row_ptr,
        const unsigned short* __restrict__ csr_src, const float* __restrict__ as,
        const float* __restrict__ ad, const float* __restrict__ b2,
        float* __restrict__ out) {
    __shared__ int            ssrc[4][64];
    __shared__ unsigned short wbf[4][64];
    int tid = threadIdx.x;
    int wv = tid >> 6, lane = tid & 63;
    int n = blockIdx.x * 4 + wv;
    if (n >= NN) return;
    int start = row_ptr[n], end = row_ptr[n + 1];
    float adv = ad[n];
    float acc = 0.f;
    float den = 0.f;
    for (int c0 = start; c0 < end; c0 += 64) {
        int m = min(64, end - c0);
        if (lane < m) {
            int s = (int)csr_src[c0 + lane];
            ssrc[wv][lane] = s;
            float e = as[s] + adv;
            e = e > 0.f ? e : 0.2f * e;
            float x = __expf(e);
            wbf[wv][lane] = f2bf(x);
            den += x;
        }
        int j = 0;
        for (; j + 8 <= m; j += 8) {
            int sj[8]; unsigned gj[8];
            #pragma unroll
            for (int u = 0; u < 8; u++) sj[u] = ssrc[wv][j + u];
            #pragma unroll
            for (int u = 0; u < 8; u++)
                gj[u] = g2b[(size_t)sj[u] * 64 + lane];
            unsigned wp01 = *(const unsigned*)&wbf[wv][j];
            unsigned wp23 = *(const unsigned*)&wbf[wv][j + 2];
            unsigned wp45 = *(const unsigned*)&wbf[wv][j + 4];
            unsigned wp67 = *(const unsigned*)&wbf[wv][j + 6];
            acc = fdot2bf(prm(gj[1], gj[0], 0x05040100), wp01, acc);
            acc = fdot2bf(prm(gj[3], gj[2], 0x05040100), wp23, acc);
            acc = fdot2bf(prm(gj[5], gj[4], 0x05040100), wp45, acc);
            acc = fdot2bf(prm(gj[7], gj[6], 0x05040100), wp67, acc);
        }
        for (; j + 2 <= m; j += 2) {
            int s0 = ssrc[wv][j], s1 = ssrc[wv][j + 1];
            unsigned g0 = g2b[(size_t)s0 * 64 + lane];
            unsigned g1 = g2b[(size_t)s1 * 64 + lane];
            unsigned wp = *(const unsigned*)&wbf[wv][j];
            acc = fdot2bf(prm(g1, g0, 0x05040100), wp, acc);
        }
        if (j < m) {
            int s = ssrc[wv][j];
            acc += bf2f(g2b[(size_t)s * 64 + lane]) * bf2f(wbf[wv][j]);
        }
    }
    #pragma unroll
    for (int off = 32; off; off >>= 1) den += __shfl_down(den, off);
    den = __shfl(den, 0);
    float inv = 1.f / (den + 1e-16f);
    float r = acc * inv + b2[lane];
    out[(size_t)n * 64 + lane] = r > 0.f ? r : expm1f(r);
}

// ---------------- launch ----------------

extern "C" void kernel_launch(void* const* d_in, const int* in_sizes, int n_in,
                              void* d_out, int out_size, void* d_ws, size_t ws_size,
                              hipStream_t stream) {
    const float* x      = (const float*)d_in[0];
    const int*   ei     = (const int*)d_in[1];
    const float* W1     = (const float*)d_in[2];
    const float* a_src1 = (const float*)d_in[3];
    const float* a_dst1 = (const float*)d_in[4];
    const float* b1     = (const float*)d_in[5];
    const float* W2     = (const float*)d_in[6];
    const float* a_src2 = (const float*)d_in[7];
    const float* a_dst2 = (const float*)d_in[8];
    const float* b2     = (const float*)d_in[9];
    float* out = (float*)d_out;

    char* base = (char*)d_ws;
    size_t off = 0;
    auto alloc = [&](size_t bytes) -> void* {
        void* p = base + off;
        off = (off + bytes + 255) & ~(size_t)255;
        return p;
    };
    int*   deg     = (int*)alloc(NN * sizeof(int));
    unsigned long long* desc = (unsigned long long*)alloc(SCAN_BLOCKS * sizeof(unsigned long long));
    unsigned short* rank = (unsigned short*)alloc(EE * sizeof(unsigned short));
    int*   row_ptr = (int*)alloc((NN + 1) * sizeof(int));
    unsigned short* csr_src = (unsigned short*)alloc(EE * sizeof(unsigned short));
    unsigned short* wnorm  = (unsigned short*)alloc((size_t)4 * EE * sizeof(unsigned short));
    unsigned short* W1Thi = (unsigned short*)alloc(256 * 128 * 2);
    unsigned short* W1Tlo = (unsigned short*)alloc(256 * 128 * 2);
    unsigned short* W2Thi = (unsigned short*)alloc(64 * 256 * 2);
    unsigned short* W2Tlo = (unsigned short*)alloc(64 * 256 * 2);
    unsigned short* h1b   = (unsigned short*)alloc((size_t)NN * 256 * 2);
    float* as1     = (float*)alloc((size_t)NN * 4 * sizeof(float));
    float* ad1     = (float*)alloc((size_t)NN * 4 * sizeof(float));
    unsigned short* h2s   = (unsigned short*)alloc((size_t)NN * 256 * 2);  // [8][NN][32]
    unsigned short* g2b   = (unsigned short*)alloc((size_t)NN * 64 * 2);
    float* as2     = (float*)alloc((size_t)NN * sizeof(float));
    float* ad2     = (float*)alloc((size_t)NN * sizeof(float));

    // deg and desc contiguous -> one memset clears both
    size_t clear_bytes = (size_t)((char*)(desc + SCAN_BLOCKS) - (char*)deg);
    hipMemsetAsync(deg, 0, clear_bytes, stream);

    front_kernel<<<EBLOCKS + 128 + 64, 256, 0, stream>>>(ei, deg, rank, W1, W1Thi, W1Tlo,
                                                         W2, W2Thi, W2Tlo);
    scan_fill_kernel<<<SCAN_BLOCKS, 256, 0, stream>>>(deg, desc, row_ptr);
    scatter_kernel<<<EBLOCKS, 256, 0, stream>>>(ei, rank, row_ptr, csr_src);

    gemm1_mfma<<<(NN + 63) / 64, 256, 0, stream>>>(x, W1Thi, W1Tlo,
                                                   a_src1, a_dst1, h1b, as1, ad1);
    wnorm_kernel<<<(NN + 3) / 4, 256, 0, stream>>>(row_ptr, csr_src, as1, ad1, wnorm);
    agg1s_kernel<<<((NN + 3) / 4) * 8, 256, 0, stream>>>(h1b, row_ptr, csr_src, wnorm,
                                                         b1, h2s);
    gemm2_mfma<<<(NN + 127) / 128, 256, 0, stream>>>(h2s, W2Thi, W2Tlo,
                                                     a_src2, a_dst2, g2b, as2, ad2);
    agg2_kernel<<<(NN + 3) / 4, 256, 0, stream>>>(g2b, row_ptr, csr_src, as2, ad2, b2, out);
}